// Round 6
// baseline (833.478 us; speedup 1.0000x reference)
//
#include <hip/hip_runtime.h>

// ALISTA on MI355X.
// d_{k+1} = soft(d_k - s*(d_k @ P - C), thr_k),  P = A^T W [2048x2048], C = y W [4096x2048]
// R6: iteration GEMM -> 4 waves, wave-tile 128x64 (LDS-read bytes -25%, MFMA-bound),
//     quad-buffered LDS, reg E/O fragment dbuf, counted vmcnt(6), XCD swizzle.
// P single-pass fp16; d_k carried as fp16 scaled by 4^-(k-1); C carried as f16.

#define NDIM 2048
#define MDIM 512
#define BATCHN 4096
#define NITER 16
#define BM 128
#define BN 128
#define BK 64

#define BM2 256
#define BN2 128
#define BK2 32
#define NKT (NDIM / BK2)   // 64 K-tiles

typedef _Float16 f16;
typedef f16 f16x8 __attribute__((ext_vector_type(8)));
typedef float f32x4 __attribute__((ext_vector_type(4)));

__device__ __forceinline__ void gload_lds16(const void* g, void* lds) {
  __builtin_amdgcn_global_load_lds(
      (const __attribute__((address_space(1))) unsigned int*)g,
      (__attribute__((address_space(3))) unsigned int*)lds, 16, 0, 0);
}

// ---------------- iteration GEMM: 256x128 block, 4 waves, wave-tile 128x64 ----------------
// A = Ds [4096][2048] f16 (K-contig), B = P [2048][2048] f16 (K-contig).
__global__ __launch_bounds__(256, 1) void alista_iter_gemm(
    const f16* __restrict__ Ds, const f16* __restrict__ P,
    const f16* __restrict__ Ch,
    const float* __restrict__ thr, const float* __restrict__ step, int it,
    float sigma, float inv_sigma, float inv_sigma_next,
    float* __restrict__ outIter, f16* __restrict__ DsNext)
{
  __shared__ __align__(16) f16 ldsA[4 * BM2 * BK2];  // 64 KB (4 bufs x 16 KB)
  __shared__ __align__(16) f16 ldsB[4 * BN2 * BK2];  // 32 KB (4 bufs x 8 KB)

  const int tid = threadIdx.x;
  const int w = tid >> 6, l = tid & 63;
  const int wm = w >> 1, wn = w & 1;      // 2M x 2N waves, per-wave 128x64
  const int h = l >> 4;                   // k-octet selector

  // XCD-aware swizzle over 256 blocks (256 % 8 == 0)
  const int bid = blockIdx.x;
  const int wgid = (bid & 7) * 32 + (bid >> 3);
  const int rowTile = (wgid >> 4) * BM2;   // 16 row tiles
  const int colTile = (wgid & 15) * BN2;   // 16 col tiles

  const f16* Abase = Ds + (size_t)rowTile * NDIM;
  const f16* Bbase = P + (size_t)colTile * NDIM;

  // stage K-tile t into buf t&3 (6 global_load_lds / thread: A 4 rounds, B 2).
  // T2 swizzle: linear LDS dest, source granule pre-swizzled with the SAME
  // involution used on reads (rule #21).  s = (row>>1)&3.
  auto stage = [&](int t) {
    const int buf = t & 3;
#pragma unroll
    for (int r = 0; r < 4; ++r) {  // A tile 256x32
      int row = r * 64 + (tid >> 2);
      int colb = ((tid & 3) << 4) ^ (((row >> 1) & 3) << 4);
      gload_lds16((const char*)(Abase + (size_t)row * NDIM + t * BK2) + colb,
                  (char*)ldsA + buf * 16384 + r * 4096 + tid * 16);
    }
#pragma unroll
    for (int r = 0; r < 2; ++r) {  // B tile 128x32
      int row = r * 64 + (tid >> 2);
      int colb = ((tid & 3) << 4) ^ (((row >> 1) & 3) << 4);
      gload_lds16((const char*)(Bbase + (size_t)row * NDIM + t * BK2) + colb,
                  (char*)ldsB + buf * 8192 + r * 4096 + tid * 16);
    }
  };

// fragment reads from buf (t&3) with swizzled addresses into named regs
#define READ_FRAGS(t, af, bf)                                                   \
  {                                                                             \
    const f16* bA_ = ldsA + ((t) & 3) * 8192;                                   \
    const f16* bB_ = ldsB + ((t) & 3) * 4096;                                   \
    _Pragma("unroll")                                                           \
    for (int m = 0; m < 8; ++m) {                                               \
      int row = wm * 128 + m * 16 + (l & 15);                                   \
      af[m] = *(const f16x8*)(bA_ + row * 32 + ((h ^ ((row >> 1) & 3)) << 3));  \
    }                                                                           \
    _Pragma("unroll")                                                           \
    for (int n = 0; n < 4; ++n) {                                               \
      int row = wn * 64 + n * 16 + (l & 15);                                    \
      bf[n] = *(const f16x8*)(bB_ + row * 32 + ((h ^ ((row >> 1) & 3)) << 3));  \
    }                                                                           \
  }

#define MFMA_CLUSTER(af, bf)                                                    \
  __builtin_amdgcn_s_setprio(1);                                                \
  _Pragma("unroll")                                                             \
  for (int m = 0; m < 8; ++m)                                                   \
    _Pragma("unroll")                                                           \
    for (int n = 0; n < 4; ++n)                                                 \
      acc[m][n] = __builtin_amdgcn_mfma_f32_16x16x32_f16(af[m], bf[n],          \
                                                         acc[m][n], 0, 0, 0);   \
  __builtin_amdgcn_s_setprio(0);

  // prologue: tiles 0,1 staged; wait tile 0; read frags 0; stage 2; wait tile 1
  stage(0);
  stage(1);
  asm volatile("s_waitcnt vmcnt(6)" ::: "memory");   // tile 0 landed
  __builtin_amdgcn_s_barrier();

  f32x4 acc[8][4] = {};
  f16x8 afE[8], bfE[4], afO[8], bfO[4];   // even/odd register sets

  READ_FRAGS(0, afE, bfE);
  stage(2);
  asm volatile("s_waitcnt vmcnt(6)" ::: "memory");   // tile 1 landed (tile 2 in flight)
  __builtin_amdgcn_s_barrier();
  __builtin_amdgcn_sched_barrier(0);

  // invariant at top of iter t (even): frags t in E-regs; LDS has t+1 landed; t+2 in flight
  for (int t = 0; t < NKT; t += 2) {
    // ---- half 1: MFMA tile t (E), read frags t+1 (O), stage t+3 ----
    READ_FRAGS(t + 1, afO, bfO);
    if (t + 3 < NKT) stage(t + 3);       // overwrites buf (t-1)&3: reads drained 2 barriers ago
    __builtin_amdgcn_sched_barrier(0);
    MFMA_CLUSTER(afE, bfE);
    if (t + 3 < NKT) asm volatile("s_waitcnt vmcnt(6)" ::: "memory");  // t+2 landed
    else             asm volatile("s_waitcnt vmcnt(0)" ::: "memory");
    __builtin_amdgcn_s_barrier();
    __builtin_amdgcn_sched_barrier(0);

    // ---- half 2: MFMA tile t+1 (O), read frags t+2 (E), stage t+4 ----
    if (t + 2 < NKT) READ_FRAGS(t + 2, afE, bfE);
    if (t + 4 < NKT) stage(t + 4);       // overwrites buf t&3
    __builtin_amdgcn_sched_barrier(0);
    MFMA_CLUSTER(afO, bfO);
    if (t + 4 < NKT) asm volatile("s_waitcnt vmcnt(6)" ::: "memory");  // t+3 landed
    else             asm volatile("s_waitcnt vmcnt(0)" ::: "memory");
    __builtin_amdgcn_s_barrier();
    __builtin_amdgcn_sched_barrier(0);
  }

  // fused ALISTA epilogue. C/D layout: col = lane&15, row = 4*(lane>>4) + reg
  const int baseRow = rowTile + wm * 128 + (h << 2);
  const int baseCol = colTile + wn * 64 + (l & 15);
  const float s = step[it];
  const float tt = thr[it];
  const size_t itOff = (size_t)it * (size_t)BATCHN * NDIM;
#pragma unroll
  for (int m = 0; m < 8; ++m)
#pragma unroll
    for (int n = 0; n < 4; ++n)
#pragma unroll
      for (int r = 0; r < 4; ++r) {
        int row = baseRow + m * 16 + r;
        int col = baseCol + n * 16;
        size_t g = (size_t)row * NDIM + col;
        float v = acc[m][n][r];
        float ds = (float)Ds[g];
        float cv = (float)Ch[g];
        float z = sigma * (ds - s * (v - cv * inv_sigma));
        float az = __builtin_fabsf(z) - tt;
        float dn = az > 0.f ? (z > 0.f ? az : -az) : 0.f;
        outIter[itOff + g] = dn;
        DsNext[g] = (f16)(dn * inv_sigma_next);
      }
#undef READ_FRAGS
#undef MFMA_CLUSTER
}

// ---------------- precompute GEMM (single-pass fp16, R1 structure) ----------------
// C[row,col] = sum_k A[row,k]*B[col,k]; A [M][K] f16 K-contig, B [N][K] f16 K-contig.
__global__ __launch_bounds__(256, 2) void gemm_pre(
    const f16* __restrict__ Ap, const f16* __restrict__ Bp, int K,
    f16* __restrict__ outH)
{
  __shared__ __align__(16) f16 ldsA[BM * BK];
  __shared__ __align__(16) f16 ldsB[BN * BK];
  int t = threadIdx.x;
  int w = t >> 6, l = t & 63;
  int wr = w >> 1, wc = w & 1;
  int rowTile = blockIdx.y * BM;
  int colTile = blockIdx.x * BN;

  f32x4 acc[4][4] = {};
  const f16* Arow = Ap + (size_t)rowTile * K;
  const f16* Brow = Bp + (size_t)colTile * K;
  for (int kt = 0; kt < K; kt += BK) {
    __syncthreads();
#pragma unroll
    for (int n = 0; n < 4; ++n) {
      int e = n * 2048 + t * 8;
      int r = e >> 6, c = e & 63;
      gload_lds16(Arow + (size_t)r * K + kt + c, (char*)ldsA + n * 4096 + w * 1024);
    }
#pragma unroll
    for (int n = 0; n < 4; ++n) {
      int e = n * 2048 + t * 8;
      int r = e >> 6, c = e & 63;
      gload_lds16(Brow + (size_t)r * K + kt + c, (char*)ldsB + n * 4096 + w * 1024);
    }
    asm volatile("s_waitcnt vmcnt(0)" ::: "memory");
    __syncthreads();
#pragma unroll
    for (int ks = 0; ks < 2; ++ks) {
      f16x8 a[4], b[4];
#pragma unroll
      for (int m = 0; m < 4; ++m)
        a[m] = *(const f16x8*)(ldsA + ((wr * 64 + m * 16 + (l & 15)) * BK + ks * 32 + (l >> 4) * 8));
#pragma unroll
      for (int n = 0; n < 4; ++n)
        b[n] = *(const f16x8*)(ldsB + ((wc * 64 + n * 16 + (l & 15)) * BK + ks * 32 + (l >> 4) * 8));
#pragma unroll
      for (int m = 0; m < 4; ++m)
#pragma unroll
        for (int n = 0; n < 4; ++n)
          acc[m][n] = __builtin_amdgcn_mfma_f32_16x16x32_f16(a[m], b[n], acc[m][n], 0, 0, 0);
    }
  }

  int baseRow = rowTile + wr * 64 + ((l >> 4) << 2);
  int baseCol = colTile + wc * 64 + (l & 15);
#pragma unroll
  for (int m = 0; m < 4; ++m)
#pragma unroll
    for (int n = 0; n < 4; ++n)
#pragma unroll
      for (int r = 0; r < 4; ++r) {
        size_t g = (size_t)(baseRow + m * 16 + r) * NDIM + baseCol + n * 16;
        outH[g] = (f16)acc[m][n][r];
      }
}

// in [512,2048] f32 -> transposed fp16 [2048,512]
__global__ __launch_bounds__(256) void trans_h(
    const float* __restrict__ in, f16* __restrict__ oh)
{
  __shared__ float tile[64][65];
  int t = threadIdx.x;
  int tr = t >> 6;
  int tc = t & 63;
  int r0 = blockIdx.y * 64;
  int c0 = blockIdx.x * 64;
#pragma unroll
  for (int i = 0; i < 16; ++i) {
    int r = i * 4 + tr;
    tile[r][tc] = in[(size_t)(r0 + r) * NDIM + c0 + tc];
  }
  __syncthreads();
#pragma unroll
  for (int i = 0; i < 16; ++i) {
    int r = i * 4 + tr;
    oh[(size_t)(c0 + r) * MDIM + r0 + tc] = (f16)tile[tc][r];
  }
}

__global__ __launch_bounds__(256) void tofp16(
    const float* __restrict__ in, f16* __restrict__ oh)
{
  size_t i = (size_t)blockIdx.x * 256 + threadIdx.x;
  oh[i] = (f16)in[i];
}

// iterate 0: d1 = soft(s0*C, thr0); out[0] = d1; Ds1 = fp16(d1)  (sigma_1 = 1)
__global__ __launch_bounds__(256) void alista_iter0(
    const f16* __restrict__ Ch, const float* __restrict__ thr,
    const float* __restrict__ step, float* __restrict__ out, f16* __restrict__ Ds1)
{
  size_t i = (size_t)blockIdx.x * 256 + threadIdx.x;
  float s = step[0], tt = thr[0];
  float z = s * (float)Ch[i];
  float az = __builtin_fabsf(z) - tt;
  float dn = az > 0.f ? (z > 0.f ? az : -az) : 0.f;
  out[i] = dn;
  Ds1[i] = (f16)dn;
}

extern "C" void kernel_launch(void* const* d_in, const int* in_sizes, int n_in,
                              void* d_out, int out_size, void* d_ws, size_t ws_size,
                              hipStream_t stream)
{
  const float* y    = (const float*)d_in[0];
  const float* A    = (const float*)d_in[1];
  const float* W    = (const float*)d_in[2];
  const float* thr  = (const float*)d_in[3];
  const float* step = (const float*)d_in[4];
  float* out = (float*)d_out;
  char* ws = (char*)d_ws;

  // ws layout (56 MB):
  f16* Pht = (f16*)(ws + 0);                // 8 MB   P^T  [2048,2048] f16
  f16* Ch  = (f16*)(ws + (8ull  << 20));    // 16 MB  C = yW [4096,2048] f16
  f16* DsA = (f16*)(ws + (24ull << 20));    // 16 MB  d scaled fp16 (ping)
  f16* DsB = (f16*)(ws + (40ull << 20));    // 16 MB  (pong)
  // precompute temps alias DsA/DsB (dead before iter0/iter1 write them):
  f16* Wth = (f16*)(ws + (24ull << 20));    // 2 MB  W^T f16 [2048,512]
  f16* Ath = (f16*)(ws + (26ull << 20));    // 2 MB  A^T f16 [2048,512]
  f16* yh  = (f16*)(ws + (40ull << 20));    // 4 MB  y  f16 [4096,512]

  trans_h<<<dim3(32, 8), 256, 0, stream>>>(A, Ath);
  trans_h<<<dim3(32, 8), 256, 0, stream>>>(W, Wth);
  tofp16<<<(BATCHN * MDIM) / 256, 256, 0, stream>>>(y, yh);

  // P^T = Wt @ At^T (K=512) -> f16
  gemm_pre<<<dim3(16, 16), 256, 0, stream>>>(Wth, Ath, MDIM, Pht);
  // C = y @ W (K=512) -> f16
  gemm_pre<<<dim3(16, 32), 256, 0, stream>>>(yh, Wth, MDIM, Ch);

  alista_iter0<<<(BATCHN * NDIM) / 256, 256, 0, stream>>>(Ch, thr, step, out, DsA);

  f16* cur = DsA;
  f16* nxt = DsB;
  float sigma = 1.0f;  // sigma_k = 4^(k-1)
  for (int it = 1; it < NITER; ++it) {
    alista_iter_gemm<<<dim3(256), 256, 0, stream>>>(
        cur, Pht, Ch, thr, step, it,
        sigma, 1.0f / sigma, 0.25f / sigma, out, nxt);
    sigma *= 4.0f;
    f16* tmp = cur; cur = nxt; nxt = tmp;
  }
}